// Round 8
// baseline (410.196 us; speedup 1.0000x reference)
//
#include <hip/hip_runtime.h>
#include <cstdint>

#define NN 4
#define CC 64
#define VV 25
#define TT 300
#define MM 2
#define HH 8
#define HD 32
#define EE 256

typedef short bf16x8 __attribute__((ext_vector_type(8)));
typedef float f32x4 __attribute__((ext_vector_type(4)));

__device__ __forceinline__ unsigned short f2bf(float f) {
  union { float f; unsigned u; } x; x.f = f;
  unsigned r = x.u + 0x7FFF + ((x.u >> 16) & 1);  // RNE
  return (unsigned short)(r >> 16);
}
__device__ __forceinline__ float bf2f(unsigned short s) {
  union { unsigned u; float f; } x; x.u = ((unsigned)s) << 16;
  return x.f;
}
__device__ __forceinline__ float bperm(int byteaddr, float v) {
  return __int_as_float(__builtin_amdgcn_ds_bpermute(byteaddr, __float_as_int(v)));
}

// ws layout (unsigned short units):
//   Qh,Ql,Kh,Kl : [b,v,h,t<300,d] (15,360,000 each) [Q xlog2e, K x1/16]
//   Vt : [b,v,h,d][t pad 320] (16,384,000)
//   Oh,Ol : [b,v,t<300,e] (15,360,000 each)
//   WhT,WlT [c][e] (16,384 each); WqTh,WqTl [e][c] (49,152 each);
//   btPad [660][32] bf16, rows 20..618 = bias_table, else 0 (21,120)
#define QKN 15360000
#define VTN 16384000
#define LOG2E 1.4426950408889634f

// ---------------- prep: transpose/split weights + bf16 bias table ----------------
__global__ __launch_bounds__(256) void prep_kernel(
    const float* __restrict__ w_qkv, const float* __restrict__ w_merge,
    const float* __restrict__ bias_table,
    unsigned short* __restrict__ WqTh, unsigned short* __restrict__ WqTl,
    unsigned short* __restrict__ WhT, unsigned short* __restrict__ WlT,
    unsigned short* __restrict__ btPad)
{
  int i = blockIdx.x * 256 + threadIdx.x;
  if (i < 49152) {                      // w_qkv [c][768] -> [e][c] hi/lo
    int c = i / 768, e = i % 768;
    float v = w_qkv[i];
    unsigned short hb = f2bf(v);
    WqTh[e * 64 + c] = hb; WqTl[e * 64 + c] = f2bf(v - bf2f(hb));
  } else if (i < 65536) {               // w_merge [e][64] -> [c][e] hi/lo
    int j = i - 49152;
    int e = j >> 6, c = j & 63;
    float v = w_merge[j];
    unsigned short hb = f2bf(v);
    WhT[c * EE + e] = hb; WlT[c * EE + e] = f2bf(v - bf2f(hb));
  } else if (i < 65536 + 21120) {       // bias_table -> padded bf16
    int j = i - 65536;
    int row = j >> 5, d = j & 31;
    int g = row - 20;
    float v = (g >= 0 && g < 2 * TT - 1) ? bias_table[g * 32 + d] : 0.f;
    btPad[j] = f2bf(v);
  }
}

// ---------------- Kernel A: QKV projection via MFMA (unchanged, known-good) ----------------
__global__ __launch_bounds__(256, 3) void qkv_kernel(
    const float* __restrict__ x, const float* __restrict__ b_qkv,
    const unsigned short* __restrict__ WqTh, const unsigned short* __restrict__ WqTl,
    unsigned short* __restrict__ Qh, unsigned short* __restrict__ Ql,
    unsigned short* __restrict__ Kh, unsigned short* __restrict__ Kl,
    unsigned short* __restrict__ Vt)
{
  __shared__ union {
    float a[64 * 69];             // sA[c][t], stride 69
    unsigned short vtr[256 * 66]; // V transpose buffer [e'][t]
  } sm;

  int blk = blockIdx.x;
  int tt = blk % 5; blk /= 5;
  int v25 = blk % 25; int b = blk / 25;
  int n = b >> 1, m = b & 1;
  int t0 = tt * 60;
  int tid = threadIdx.x;
  int w = tid >> 6, lane = tid & 63, quad = lane >> 4, c16 = lane & 15;

  for (int i = tid; i < 64 * 64; i += 256) {
    int c = i >> 6, t = i & 63;
    float val = 0.f;
    if (t < 60) val = x[((((size_t)n * CC + c) * VV + v25) * TT + (t0 + t)) * MM + m];
    sm.a[c * 69 + t] = val;
  }
  __syncthreads();

  bf16x8 ah[4][2], al[4][2];
  #pragma unroll
  for (int mt = 0; mt < 4; ++mt)
    #pragma unroll
    for (int kc = 0; kc < 2; ++kc)
      #pragma unroll
      for (int j = 0; j < 8; ++j) {
        float f = sm.a[(kc * 32 + quad * 8 + j) * 69 + mt * 16 + c16];
        unsigned short hb = f2bf(f);
        ah[mt][kc][j] = (short)hb;
        al[mt][kc][j] = (short)f2bf(f - bf2f(hb));
      }
  __syncthreads();  // sA dead; sVt (union) may be written

  size_t bv = (size_t)(b * VV + v25);
  int e0 = w * 192;
  for (int nt = 0; nt < 12; ++nt) {
    int ebase = e0 + nt * 16;
    int e = ebase + c16;
    bf16x8 bh[2], bl[2];
    #pragma unroll
    for (int kc = 0; kc < 2; ++kc) {
      bh[kc] = *(const bf16x8*)&WqTh[(size_t)e * 64 + kc * 32 + quad * 8];
      bl[kc] = *(const bf16x8*)&WqTl[(size_t)e * 64 + kc * 32 + quad * 8];
    }
    f32x4 acc[4];
    #pragma unroll
    for (int mt = 0; mt < 4; ++mt) {
      acc[mt] = (f32x4){0.f, 0.f, 0.f, 0.f};
      #pragma unroll
      for (int kc = 0; kc < 2; ++kc) {
        acc[mt] = __builtin_amdgcn_mfma_f32_16x16x32_bf16(ah[mt][kc], bh[kc], acc[mt], 0, 0, 0);
        acc[mt] = __builtin_amdgcn_mfma_f32_16x16x32_bf16(al[mt][kc], bh[kc], acc[mt], 0, 0, 0);
        acc[mt] = __builtin_amdgcn_mfma_f32_16x16x32_bf16(ah[mt][kc], bl[kc], acc[mt], 0, 0, 0);
      }
    }
    float bias = b_qkv[e];
    int which = ebase >> 8;  // wave-uniform
    if (which < 2) {
      float sc = (which == 0) ? LOG2E : 0.0625f;
      unsigned short* Dh = (which == 0) ? Qh : Kh;
      unsigned short* Dl = (which == 0) ? Ql : Kl;
      int hh = (e >> 5) & 7, dd = e & 31;
      size_t rowb = (bv * HH + hh) * TT;
      #pragma unroll
      for (int mt = 0; mt < 4; ++mt)
        #pragma unroll
        for (int reg = 0; reg < 4; ++reg) {
          int lrow = mt * 16 + quad * 4 + reg;
          // rows >= 60 would RACE with the next tt-block (zero-staged x)
          if (lrow < 60) {
            int t = t0 + lrow;
            float s = (acc[mt][reg] + bias) * sc;
            unsigned short hb = f2bf(s);
            size_t idx = (rowb + t) * HD + dd;
            Dh[idx] = hb; Dl[idx] = f2bf(s - bf2f(hb));
          }
        }
    } else {
      int ep = e - 512;
      #pragma unroll
      for (int mt = 0; mt < 4; ++mt)
        #pragma unroll
        for (int reg = 0; reg < 4; ++reg)
          sm.vtr[ep * 66 + mt * 16 + quad * 4 + reg] = f2bf(acc[mt][reg] + bias);
    }
  }
  __syncthreads();
  for (int i = tid; i < 256 * 30; i += 256) {
    int ep = i / 30, tc = (i % 30) * 2;
    int e = 512 + ep;
    int hh = (e >> 5) & 7, dd = e & 31;
    size_t idx = ((bv * HH + hh) * HD + dd) * 320 + t0 + tc;
    *(unsigned int*)&Vt[idx] = *(const unsigned int*)&sm.vtr[ep * 66 + tc];
    // Vt rows t in [300,320) stay poison (finite bf16) -> always hit P=0.
  }
}

// ---------------- Kernel B: MFMA attention, bpermute R-gather, 6 blocks/CU ----------------
// block=(b,v,h,lt): 8000 blocks, 4 waves; wave w owns S rows [16w,16w+16).
// R C-layout output is a within-quad lane permutation of the S C-init:
// needed col = 63+4q+reg-16nt-c16; (col&15) is nt-invariant -> one bpermute
// per (n5,reg) = 20/rt; n5 = a-nt with per-lane constant a = sel ? 4 : 3.
// No R LDS buffer; sPh double-buffered -> no inter-rt WAR hazards.
__global__ __launch_bounds__(256, 6) void attn6_kernel(
    const unsigned short* __restrict__ Qh, const unsigned short* __restrict__ Ql,
    const unsigned short* __restrict__ Kh, const unsigned short* __restrict__ Kl,
    const unsigned short* __restrict__ Vt, const unsigned short* __restrict__ btPad,
    unsigned short* __restrict__ Oh, unsigned short* __restrict__ Ol)
{
  __shared__ __align__(16) unsigned short sPh[2][64 * 72];  // 18,432 B, rows wave-private

  int bid = blockIdx.x;
  int lt = bid % 5; int rest = bid / 5;
  int h = rest & 7; rest >>= 3;
  int v = rest % 25; int b = rest / 25;
  int l0 = lt * 64;
  int tid = threadIdx.x;
  int w = tid >> 6, lane = tid & 63, quad = lane >> 4, c16 = lane & 15;
  size_t tbase = ((size_t)(b * VV + v) * HH + h) * TT;
  size_t vbase = ((size_t)(b * VV + v) * HH + h) * HD;

  bf16x8 qh, qlw;
  {
    size_t qo = (tbase + l0 + w * 16 + c16) * HD + quad * 8;
    qh  = *(const bf16x8*)&Qh[qo];
    qlw = *(const bf16x8*)&Ql[qo];
  }

  // rt-invariant bpermute addresses + selects (per reg)
  int srcaddr[4]; bool sel[4];
  #pragma unroll
  for (int reg = 0; reg < 4; ++reg) {
    srcaddr[reg] = 4 * (quad * 16 + ((15 + 4 * quad + reg - c16) & 15));
    sel[reg] = (4 * quad + reg) > c16;   // a==4
  }

  f32x4 accO[2];
  accO[0] = (f32x4){0.f, 0.f, 0.f, 0.f};
  accO[1] = (f32x4){0.f, 0.f, 0.f, 0.f};
  float psum[4] = {0.f, 0.f, 0.f, 0.f};

  for (int rt = 0; rt < 5; ++rt) {
    int r0 = rt * 64;
    unsigned short* myP = &sPh[rt & 1][16 * w * 72];

    // ---- R phase: 5 MFMA from global btPad (L2-hot), then 20 bpermutes ----
    const unsigned short* btb = &btPad[(size_t)(l0 + 256 + 16 * w - r0 + c16) * HD + quad * 8];
    f32x4 r5[5];
    #pragma unroll
    for (int n5 = 0; n5 < 5; ++n5) {
      bf16x8 bfr = *(const bf16x8*)&btb[n5 * 16 * HD];
      f32x4 r = {0.f, 0.f, 0.f, 0.f};
      r5[n5] = __builtin_amdgcn_mfma_f32_16x16x32_bf16(qh, bfr, r, 0, 0, 0);
    }
    float B5[5][4];
    #pragma unroll
    for (int n5 = 0; n5 < 5; ++n5)
      #pragma unroll
      for (int reg = 0; reg < 4; ++reg)
        B5[n5][reg] = bperm(srcaddr[reg], r5[n5][reg]);

    // ---- S = QK (3 MFMA, C=0) ----
    const unsigned short* kb = &Kh[(tbase + r0 + c16) * HD + quad * 8];
    const unsigned short* lb = &Kl[(tbase + r0 + c16) * HD + quad * 8];
    f32x4 sc4[4];
    #pragma unroll
    for (int nt = 0; nt < 4; ++nt) {
      bf16x8 khf = *(const bf16x8*)&kb[nt * 16 * HD];
      bf16x8 klf = *(const bf16x8*)&lb[nt * 16 * HD];
      f32x4 c = {0.f, 0.f, 0.f, 0.f};
      c = __builtin_amdgcn_mfma_f32_16x16x32_bf16(qh,  khf, c, 0, 0, 0);
      c = __builtin_amdgcn_mfma_f32_16x16x32_bf16(qlw, khf, c, 0, 0, 0);
      c = __builtin_amdgcn_mfma_f32_16x16x32_bf16(qh,  klf, c, 0, 0, 0);
      sc4[nt] = c;
    }
    // ---- add R (selected bpermute result), exp2, P store ----
    #pragma unroll
    for (int nt = 0; nt < 4; ++nt) {
      bool bad = (r0 + nt * 16 + c16) >= TT;
      #pragma unroll
      for (int reg = 0; reg < 4; ++reg) {
        float ri = sel[reg] ? B5[4 - nt][reg] : B5[3 - nt][reg];
        float p = bad ? 0.f : __builtin_amdgcn_exp2f(sc4[nt][reg] + ri);
        psum[reg] += p;
        myP[(4 * quad + reg) * 72 + nt * 16 + c16] = f2bf(p);
      }
    }
    // ---- PV ----
    #pragma unroll
    for (int kc = 0; kc < 2; ++kc) {
      bf16x8 pf = *(const bf16x8*)&myP[c16 * 72 + kc * 32 + quad * 8];
      #pragma unroll
      for (int no = 0; no < 2; ++no) {
        bf16x8 vfr = *(const bf16x8*)&Vt[(vbase + no * 16 + c16) * 320 + r0 + kc * 32 + quad * 8];
        accO[no] = __builtin_amdgcn_mfma_f32_16x16x32_bf16(pf, vfr, accO[no], 0, 0, 0);
      }
    }
  }

  // ---- row-sum reduce + epilogue ----
  #pragma unroll
  for (int reg = 0; reg < 4; ++reg) {
    #pragma unroll
    for (int off = 1; off <= 8; off <<= 1)
      psum[reg] += __shfl_xor(psum[reg], off);
  }
  size_t obase = (size_t)(b * VV + v) * TT;
  #pragma unroll
  for (int no = 0; no < 2; ++no)
    #pragma unroll
    for (int reg = 0; reg < 4; ++reg) {
      int l_loc = 16 * w + 4 * quad + reg;
      int gl = l0 + l_loc;
      if (gl < TT) {
        float o = accO[no][reg] / psum[reg];
        size_t oi = (obase + gl) * EE + h * HD + no * 16 + c16;
        unsigned short hb = f2bf(o);
        Oh[oi] = hb; Ol[oi] = f2bf(o - bf2f(hb));
      }
    }
}

// ---------------- Kernel C: merge projection, 2000 blocks (t-tiles of 30) ----------------
__global__ __launch_bounds__(256, 4) void merge3_kernel(
    const unsigned short* __restrict__ Oh, const unsigned short* __restrict__ Ol,
    const unsigned short* __restrict__ WhT, const unsigned short* __restrict__ WlT,
    const float* __restrict__ b_merge, float* __restrict__ out)
{
  int blk = blockIdx.x;
  int tt = blk % 10; blk /= 10;
  int v = blk % 25; int b = blk / 25;
  int nb = b >> 1, mm = b & 1;
  int tid = threadIdx.x;
  int w = tid >> 6, lane = tid & 63, quad = lane >> 4, c16 = lane & 15;
  size_t obase = (size_t)(b * VV + v) * TT;
  int t0 = tt * 30;
  int cidx = w * 16 + c16;

  f32x4 acc[2];
  acc[0] = (f32x4){0.f, 0.f, 0.f, 0.f};
  acc[1] = (f32x4){0.f, 0.f, 0.f, 0.f};

  for (int ks = 0; ks < 8; ++ks) {
    int eoff = ks * 32 + quad * 8;
    // A rows with t >= owned range read ws garbage (finite bf16) but only
    // produce discarded D rows -> no load guard needed.
    bf16x8 bh = *(const bf16x8*)&WhT[(size_t)cidx * EE + eoff];
    bf16x8 bl = *(const bf16x8*)&WlT[(size_t)cidx * EE + eoff];
    bf16x8 ahv[2], alv[2];
    #pragma unroll
    for (int mt = 0; mt < 2; ++mt) {
      size_t ao = (obase + t0 + mt * 16 + c16) * EE + eoff;
      ahv[mt] = *(const bf16x8*)&Oh[ao];
      alv[mt] = *(const bf16x8*)&Ol[ao];
    }
    #pragma unroll
    for (int mt = 0; mt < 2; ++mt) {
      acc[mt] = __builtin_amdgcn_mfma_f32_16x16x32_bf16(ahv[mt], bh, acc[mt], 0, 0, 0);
      acc[mt] = __builtin_amdgcn_mfma_f32_16x16x32_bf16(alv[mt], bh, acc[mt], 0, 0, 0);
      acc[mt] = __builtin_amdgcn_mfma_f32_16x16x32_bf16(ahv[mt], bl, acc[mt], 0, 0, 0);
    }
  }
  float bm = b_merge[cidx];
  #pragma unroll
  for (int mt = 0; mt < 2; ++mt)
    #pragma unroll
    for (int reg = 0; reg < 4; ++reg) {
      int lrow = mt * 16 + 4 * quad + reg;
      if (lrow < 30) {
        int t = t0 + lrow;
        out[(((size_t)nb * CC + cidx) * VV + v) * TT * MM + (size_t)t * MM + mm]
            = acc[mt][reg] + bm;
      }
    }
}

extern "C" void kernel_launch(void* const* d_in, const int* in_sizes, int n_in,
                              void* d_out, int out_size, void* d_ws, size_t ws_size,
                              hipStream_t stream) {
  const float* x          = (const float*)d_in[0];
  const float* w_qkv      = (const float*)d_in[1];
  const float* b_qkv      = (const float*)d_in[2];
  const float* w_merge    = (const float*)d_in[3];
  const float* b_merge    = (const float*)d_in[4];
  const float* bias_table = (const float*)d_in[5];
  float* out = (float*)d_out;
  unsigned short* ws16 = (unsigned short*)d_ws;
  unsigned short* Qh   = ws16;
  unsigned short* Ql   = ws16 + (size_t)QKN;
  unsigned short* Kh   = ws16 + (size_t)2 * QKN;
  unsigned short* Kl   = ws16 + (size_t)3 * QKN;
  unsigned short* Vt   = ws16 + (size_t)4 * QKN;
  unsigned short* Oh   = ws16 + (size_t)4 * QKN + VTN;
  unsigned short* Ol   = ws16 + (size_t)5 * QKN + VTN;
  unsigned short* base8 = ws16 + (size_t)6 * QKN + VTN;
  unsigned short* WhT  = base8;
  unsigned short* WlT  = base8 + 16384;
  unsigned short* WqTh = base8 + 32768;
  unsigned short* WqTl = base8 + 81920;
  unsigned short* btPad = base8 + 131072;

  prep_kernel<<<dim3(339), dim3(256), 0, stream>>>(w_qkv, w_merge, bias_table,
                                                   WqTh, WqTl, WhT, WlT, btPad);
  qkv_kernel<<<dim3(1000), dim3(256), 0, stream>>>(x, b_qkv, WqTh, WqTl,
                                                   Qh, Ql, Kh, Kl, Vt);
  attn6_kernel<<<dim3(8000), dim3(256), 0, stream>>>(Qh, Ql, Kh, Kl, Vt, btPad, Oh, Ol);
  merge3_kernel<<<dim3(2000), dim3(256), 0, stream>>>(Oh, Ol, WhT, WlT, b_merge, out);
}

// Round 9
// 375.413 us; speedup vs baseline: 1.0927x; 1.0927x over previous
//
#include <hip/hip_runtime.h>
#include <cstdint>

#define NN 4
#define CC 64
#define VV 25
#define TT 300
#define MM 2
#define HH 8
#define HD 32
#define EE 256

typedef short bf16x8 __attribute__((ext_vector_type(8)));
typedef float f32x4 __attribute__((ext_vector_type(4)));

__device__ __forceinline__ unsigned short f2bf(float f) {
  union { float f; unsigned u; } x; x.f = f;
  unsigned r = x.u + 0x7FFF + ((x.u >> 16) & 1);  // RNE
  return (unsigned short)(r >> 16);
}
__device__ __forceinline__ float bf2f(unsigned short s) {
  union { unsigned u; float f; } x; x.u = ((unsigned)s) << 16;
  return x.f;
}
__device__ __forceinline__ float bperm(int byteaddr, float v) {
  return __int_as_float(__builtin_amdgcn_ds_bpermute(byteaddr, __float_as_int(v)));
}

// ws layout (unsigned short units):
//   Qh,Ql,Kh,Kl : [b,v,h,t<300,d] (15,360,000 each) [Q xlog2e, K x1/16]
//   Vt : [b,v,h,d][t pad 320] (16,384,000)
//   Oh,Ol : [b,v,t<300,e] (15,360,000 each)
//   WhT,WlT [c][e] (16,384 each); WqTh,WqTl [e][c] (49,152 each);
//   btPad [660][32] bf16, rows 20..618 = bias_table, else 0 (21,120)
#define QKN 15360000
#define VTN 16384000
#define LOG2E 1.4426950408889634f

// ---------------- prep: transpose/split weights + bf16 bias table ----------------
__global__ __launch_bounds__(256) void prep_kernel(
    const float* __restrict__ w_qkv, const float* __restrict__ w_merge,
    const float* __restrict__ bias_table,
    unsigned short* __restrict__ WqTh, unsigned short* __restrict__ WqTl,
    unsigned short* __restrict__ WhT, unsigned short* __restrict__ WlT,
    unsigned short* __restrict__ btPad)
{
  int i = blockIdx.x * 256 + threadIdx.x;
  if (i < 49152) {                      // w_qkv [c][768] -> [e][c] hi/lo
    int c = i / 768, e = i % 768;
    float v = w_qkv[i];
    unsigned short hb = f2bf(v);
    WqTh[e * 64 + c] = hb; WqTl[e * 64 + c] = f2bf(v - bf2f(hb));
  } else if (i < 65536) {               // w_merge [e][64] -> [c][e] hi/lo
    int j = i - 49152;
    int e = j >> 6, c = j & 63;
    float v = w_merge[j];
    unsigned short hb = f2bf(v);
    WhT[c * EE + e] = hb; WlT[c * EE + e] = f2bf(v - bf2f(hb));
  } else if (i < 65536 + 21120) {       // bias_table -> padded bf16
    int j = i - 65536;
    int row = j >> 5, d = j & 31;
    int g = row - 20;
    float v = (g >= 0 && g < 2 * TT - 1) ? bias_table[g * 32 + d] : 0.f;
    btPad[j] = f2bf(v);
  }
}

// ---------------- Kernel A: QKV projection via MFMA (unchanged, known-good) ----------------
__global__ __launch_bounds__(256, 3) void qkv_kernel(
    const float* __restrict__ x, const float* __restrict__ b_qkv,
    const unsigned short* __restrict__ WqTh, const unsigned short* __restrict__ WqTl,
    unsigned short* __restrict__ Qh, unsigned short* __restrict__ Ql,
    unsigned short* __restrict__ Kh, unsigned short* __restrict__ Kl,
    unsigned short* __restrict__ Vt)
{
  __shared__ union {
    float a[64 * 69];             // sA[c][t], stride 69
    unsigned short vtr[256 * 66]; // V transpose buffer [e'][t]
  } sm;

  int blk = blockIdx.x;
  int tt = blk % 5; blk /= 5;
  int v25 = blk % 25; int b = blk / 25;
  int n = b >> 1, m = b & 1;
  int t0 = tt * 60;
  int tid = threadIdx.x;
  int w = tid >> 6, lane = tid & 63, quad = lane >> 4, c16 = lane & 15;

  for (int i = tid; i < 64 * 64; i += 256) {
    int c = i >> 6, t = i & 63;
    float val = 0.f;
    if (t < 60) val = x[((((size_t)n * CC + c) * VV + v25) * TT + (t0 + t)) * MM + m];
    sm.a[c * 69 + t] = val;
  }
  __syncthreads();

  bf16x8 ah[4][2], al[4][2];
  #pragma unroll
  for (int mt = 0; mt < 4; ++mt)
    #pragma unroll
    for (int kc = 0; kc < 2; ++kc)
      #pragma unroll
      for (int j = 0; j < 8; ++j) {
        float f = sm.a[(kc * 32 + quad * 8 + j) * 69 + mt * 16 + c16];
        unsigned short hb = f2bf(f);
        ah[mt][kc][j] = (short)hb;
        al[mt][kc][j] = (short)f2bf(f - bf2f(hb));
      }
  __syncthreads();  // sA dead; sVt (union) may be written

  size_t bv = (size_t)(b * VV + v25);
  int e0 = w * 192;
  for (int nt = 0; nt < 12; ++nt) {
    int ebase = e0 + nt * 16;
    int e = ebase + c16;
    bf16x8 bh[2], bl[2];
    #pragma unroll
    for (int kc = 0; kc < 2; ++kc) {
      bh[kc] = *(const bf16x8*)&WqTh[(size_t)e * 64 + kc * 32 + quad * 8];
      bl[kc] = *(const bf16x8*)&WqTl[(size_t)e * 64 + kc * 32 + quad * 8];
    }
    f32x4 acc[4];
    #pragma unroll
    for (int mt = 0; mt < 4; ++mt) {
      acc[mt] = (f32x4){0.f, 0.f, 0.f, 0.f};
      #pragma unroll
      for (int kc = 0; kc < 2; ++kc) {
        acc[mt] = __builtin_amdgcn_mfma_f32_16x16x32_bf16(ah[mt][kc], bh[kc], acc[mt], 0, 0, 0);
        acc[mt] = __builtin_amdgcn_mfma_f32_16x16x32_bf16(al[mt][kc], bh[kc], acc[mt], 0, 0, 0);
        acc[mt] = __builtin_amdgcn_mfma_f32_16x16x32_bf16(ah[mt][kc], bl[kc], acc[mt], 0, 0, 0);
      }
    }
    float bias = b_qkv[e];
    int which = ebase >> 8;  // wave-uniform
    if (which < 2) {
      float sc = (which == 0) ? LOG2E : 0.0625f;
      unsigned short* Dh = (which == 0) ? Qh : Kh;
      unsigned short* Dl = (which == 0) ? Ql : Kl;
      int hh = (e >> 5) & 7, dd = e & 31;
      size_t rowb = (bv * HH + hh) * TT;
      #pragma unroll
      for (int mt = 0; mt < 4; ++mt)
        #pragma unroll
        for (int reg = 0; reg < 4; ++reg) {
          int lrow = mt * 16 + quad * 4 + reg;
          // rows >= 60 would RACE with the next tt-block (zero-staged x)
          if (lrow < 60) {
            int t = t0 + lrow;
            float s = (acc[mt][reg] + bias) * sc;
            unsigned short hb = f2bf(s);
            size_t idx = (rowb + t) * HD + dd;
            Dh[idx] = hb; Dl[idx] = f2bf(s - bf2f(hb));
          }
        }
    } else {
      int ep = e - 512;
      #pragma unroll
      for (int mt = 0; mt < 4; ++mt)
        #pragma unroll
        for (int reg = 0; reg < 4; ++reg)
          sm.vtr[ep * 66 + mt * 16 + quad * 4 + reg] = f2bf(acc[mt][reg] + bias);
    }
  }
  __syncthreads();
  for (int i = tid; i < 256 * 30; i += 256) {
    int ep = i / 30, tc = (i % 30) * 2;
    int e = 512 + ep;
    int hh = (e >> 5) & 7, dd = e & 31;
    size_t idx = ((bv * HH + hh) * HD + dd) * 320 + t0 + tc;
    *(unsigned int*)&Vt[idx] = *(const unsigned int*)&sm.vtr[ep * 66 + tc];
    // Vt rows t in [300,320) stay poison (finite bf16) -> always hit P=0.
  }
}

// ---------------- Kernel B: MFMA attention, bpermute R-gather, PV pipelined ----------------
// block=(b,v,h,lt): 8000 blocks, 4 waves; wave w owns S rows [16w,16w+16).
// PV for tile rt-1 runs AFTER P(rt) is stored: the ds_write->ds_read round
// trip of tile rt is hidden behind 4 independent PV MFMAs + V loads, and
// PV's data has a full iteration of load slack. sPh double-buffered.
// launch_bounds(256,4): 128-VGPR cap -> no scratch spills (r8's 6-wave bound
// forced 40 VGPRs and ~150 MB/dispatch of spill traffic).
__global__ __launch_bounds__(256, 4) void attn7_kernel(
    const unsigned short* __restrict__ Qh, const unsigned short* __restrict__ Ql,
    const unsigned short* __restrict__ Kh, const unsigned short* __restrict__ Kl,
    const unsigned short* __restrict__ Vt, const unsigned short* __restrict__ btPad,
    unsigned short* __restrict__ Oh, unsigned short* __restrict__ Ol)
{
  __shared__ __align__(16) unsigned short sPh[2][64 * 72];  // 18,432 B, rows wave-private

  int bid = blockIdx.x;
  int lt = bid % 5; int rest = bid / 5;
  int h = rest & 7; rest >>= 3;
  int v = rest % 25; int b = rest / 25;
  int l0 = lt * 64;
  int tid = threadIdx.x;
  int w = tid >> 6, lane = tid & 63, quad = lane >> 4, c16 = lane & 15;
  size_t tbase = ((size_t)(b * VV + v) * HH + h) * TT;
  size_t vbase = ((size_t)(b * VV + v) * HH + h) * HD;

  bf16x8 qh, qlw;
  {
    size_t qo = (tbase + l0 + w * 16 + c16) * HD + quad * 8;
    qh  = *(const bf16x8*)&Qh[qo];
    qlw = *(const bf16x8*)&Ql[qo];
  }

  // rt-invariant bpermute addresses + selects (per reg)
  int srcaddr[4]; bool sel[4];
  #pragma unroll
  for (int reg = 0; reg < 4; ++reg) {
    srcaddr[reg] = 4 * (quad * 16 + ((15 + 4 * quad + reg - c16) & 15));
    sel[reg] = (4 * quad + reg) > c16;   // a==4
  }

  f32x4 accO[2];
  accO[0] = (f32x4){0.f, 0.f, 0.f, 0.f};
  accO[1] = (f32x4){0.f, 0.f, 0.f, 0.f};
  float psum[4] = {0.f, 0.f, 0.f, 0.f};

  for (int rt = 0; rt < 5; ++rt) {
    int r0 = rt * 64;
    unsigned short* myP = &sPh[rt & 1][16 * w * 72];

    // ---- loads for this tile (bt, K) + V for the PREVIOUS tile ----
    const unsigned short* btb = &btPad[(size_t)(l0 + 256 + 16 * w - r0 + c16) * HD + quad * 8];
    bf16x8 btv[5];
    #pragma unroll
    for (int n5 = 0; n5 < 5; ++n5) btv[n5] = *(const bf16x8*)&btb[n5 * 16 * HD];
    const unsigned short* kb = &Kh[(tbase + r0 + c16) * HD + quad * 8];
    const unsigned short* lb = &Kl[(tbase + r0 + c16) * HD + quad * 8];
    bf16x8 khv[4], klv[4];
    #pragma unroll
    for (int nt = 0; nt < 4; ++nt) {
      khv[nt] = *(const bf16x8*)&kb[nt * 16 * HD];
      klv[nt] = *(const bf16x8*)&lb[nt * 16 * HD];
    }
    bf16x8 vv[2][2];
    int p0 = r0 - 64;  // previous tile's base
    if (rt > 0) {
      #pragma unroll
      for (int kc = 0; kc < 2; ++kc)
        #pragma unroll
        for (int no = 0; no < 2; ++no)
          vv[kc][no] = *(const bf16x8*)&Vt[(vbase + no * 16 + c16) * 320 + p0 + kc * 32 + quad * 8];
    }

    // ---- R phase: 5 MFMA then 20 bpermutes ----
    f32x4 r5[5];
    #pragma unroll
    for (int n5 = 0; n5 < 5; ++n5) {
      f32x4 r = {0.f, 0.f, 0.f, 0.f};
      r5[n5] = __builtin_amdgcn_mfma_f32_16x16x32_bf16(qh, btv[n5], r, 0, 0, 0);
    }
    float B5[5][4];
    #pragma unroll
    for (int n5 = 0; n5 < 5; ++n5)
      #pragma unroll
      for (int reg = 0; reg < 4; ++reg)
        B5[n5][reg] = bperm(srcaddr[reg], r5[n5][reg]);

    // ---- S = QK (3 MFMA, C=0) ----
    f32x4 sc4[4];
    #pragma unroll
    for (int nt = 0; nt < 4; ++nt) {
      f32x4 c = {0.f, 0.f, 0.f, 0.f};
      c = __builtin_amdgcn_mfma_f32_16x16x32_bf16(qh,  khv[nt], c, 0, 0, 0);
      c = __builtin_amdgcn_mfma_f32_16x16x32_bf16(qlw, khv[nt], c, 0, 0, 0);
      c = __builtin_amdgcn_mfma_f32_16x16x32_bf16(qh,  klv[nt], c, 0, 0, 0);
      sc4[nt] = c;
    }
    // ---- add R, exp2, P store (buffer rt&1) ----
    #pragma unroll
    for (int nt = 0; nt < 4; ++nt) {
      bool bad = (r0 + nt * 16 + c16) >= TT;
      #pragma unroll
      for (int reg = 0; reg < 4; ++reg) {
        float ri = sel[reg] ? B5[4 - nt][reg] : B5[3 - nt][reg];
        float p = bad ? 0.f : __builtin_amdgcn_exp2f(sc4[nt][reg] + ri);
        psum[reg] += p;
        myP[(4 * quad + reg) * 72 + nt * 16 + c16] = f2bf(p);
      }
    }
    // ---- PV for PREVIOUS tile (buffer (rt-1)&1) ----
    if (rt > 0) {
      unsigned short* prevP = &sPh[(rt - 1) & 1][16 * w * 72];
      #pragma unroll
      for (int kc = 0; kc < 2; ++kc) {
        bf16x8 pf = *(const bf16x8*)&prevP[c16 * 72 + kc * 32 + quad * 8];
        #pragma unroll
        for (int no = 0; no < 2; ++no)
          accO[no] = __builtin_amdgcn_mfma_f32_16x16x32_bf16(pf, vv[kc][no], accO[no], 0, 0, 0);
      }
    }
  }
  // ---- tail PV for rt=4 (buffer 0) ----
  {
    int p0 = 4 * 64;
    unsigned short* prevP = &sPh[0][16 * w * 72];
    #pragma unroll
    for (int kc = 0; kc < 2; ++kc) {
      bf16x8 pf = *(const bf16x8*)&prevP[c16 * 72 + kc * 32 + quad * 8];
      #pragma unroll
      for (int no = 0; no < 2; ++no) {
        bf16x8 vfr = *(const bf16x8*)&Vt[(vbase + no * 16 + c16) * 320 + p0 + kc * 32 + quad * 8];
        accO[no] = __builtin_amdgcn_mfma_f32_16x16x32_bf16(pf, vfr, accO[no], 0, 0, 0);
      }
    }
  }

  // ---- row-sum reduce + epilogue ----
  #pragma unroll
  for (int reg = 0; reg < 4; ++reg) {
    #pragma unroll
    for (int off = 1; off <= 8; off <<= 1)
      psum[reg] += __shfl_xor(psum[reg], off);
  }
  size_t obase = (size_t)(b * VV + v) * TT;
  #pragma unroll
  for (int no = 0; no < 2; ++no)
    #pragma unroll
    for (int reg = 0; reg < 4; ++reg) {
      int l_loc = 16 * w + 4 * quad + reg;
      int gl = l0 + l_loc;
      if (gl < TT) {
        float o = accO[no][reg] / psum[reg];
        size_t oi = (obase + gl) * EE + h * HD + no * 16 + c16;
        unsigned short hb = f2bf(o);
        Oh[oi] = hb; Ol[oi] = f2bf(o - bf2f(hb));
      }
    }
}

// ---------------- Kernel C: merge projection, 2000 blocks (t-tiles of 30) ----------------
__global__ __launch_bounds__(256, 4) void merge3_kernel(
    const unsigned short* __restrict__ Oh, const unsigned short* __restrict__ Ol,
    const unsigned short* __restrict__ WhT, const unsigned short* __restrict__ WlT,
    const float* __restrict__ b_merge, float* __restrict__ out)
{
  int blk = blockIdx.x;
  int tt = blk % 10; blk /= 10;
  int v = blk % 25; int b = blk / 25;
  int nb = b >> 1, mm = b & 1;
  int tid = threadIdx.x;
  int w = tid >> 6, lane = tid & 63, quad = lane >> 4, c16 = lane & 15;
  size_t obase = (size_t)(b * VV + v) * TT;
  int t0 = tt * 30;
  int cidx = w * 16 + c16;

  f32x4 acc[2];
  acc[0] = (f32x4){0.f, 0.f, 0.f, 0.f};
  acc[1] = (f32x4){0.f, 0.f, 0.f, 0.f};

  for (int ks = 0; ks < 8; ++ks) {
    int eoff = ks * 32 + quad * 8;
    bf16x8 bh = *(const bf16x8*)&WhT[(size_t)cidx * EE + eoff];
    bf16x8 bl = *(const bf16x8*)&WlT[(size_t)cidx * EE + eoff];
    bf16x8 ahv[2], alv[2];
    #pragma unroll
    for (int mt = 0; mt < 2; ++mt) {
      size_t ao = (obase + t0 + mt * 16 + c16) * EE + eoff;
      ahv[mt] = *(const bf16x8*)&Oh[ao];
      alv[mt] = *(const bf16x8*)&Ol[ao];
    }
    #pragma unroll
    for (int mt = 0; mt < 2; ++mt) {
      acc[mt] = __builtin_amdgcn_mfma_f32_16x16x32_bf16(ahv[mt], bh, acc[mt], 0, 0, 0);
      acc[mt] = __builtin_amdgcn_mfma_f32_16x16x32_bf16(alv[mt], bh, acc[mt], 0, 0, 0);
      acc[mt] = __builtin_amdgcn_mfma_f32_16x16x32_bf16(ahv[mt], bl, acc[mt], 0, 0, 0);
    }
  }
  float bm = b_merge[cidx];
  #pragma unroll
  for (int mt = 0; mt < 2; ++mt)
    #pragma unroll
    for (int reg = 0; reg < 4; ++reg) {
      int lrow = mt * 16 + 4 * quad + reg;
      if (lrow < 30) {
        int t = t0 + lrow;
        out[(((size_t)nb * CC + cidx) * VV + v) * TT * MM + (size_t)t * MM + mm]
            = acc[mt][reg] + bm;
      }
    }
}

extern "C" void kernel_launch(void* const* d_in, const int* in_sizes, int n_in,
                              void* d_out, int out_size, void* d_ws, size_t ws_size,
                              hipStream_t stream) {
  const float* x          = (const float*)d_in[0];
  const float* w_qkv      = (const float*)d_in[1];
  const float* b_qkv      = (const float*)d_in[2];
  const float* w_merge    = (const float*)d_in[3];
  const float* b_merge    = (const float*)d_in[4];
  const float* bias_table = (const float*)d_in[5];
  float* out = (float*)d_out;
  unsigned short* ws16 = (unsigned short*)d_ws;
  unsigned short* Qh   = ws16;
  unsigned short* Ql   = ws16 + (size_t)QKN;
  unsigned short* Kh   = ws16 + (size_t)2 * QKN;
  unsigned short* Kl   = ws16 + (size_t)3 * QKN;
  unsigned short* Vt   = ws16 + (size_t)4 * QKN;
  unsigned short* Oh   = ws16 + (size_t)4 * QKN + VTN;
  unsigned short* Ol   = ws16 + (size_t)5 * QKN + VTN;
  unsigned short* base8 = ws16 + (size_t)6 * QKN + VTN;
  unsigned short* WhT  = base8;
  unsigned short* WlT  = base8 + 16384;
  unsigned short* WqTh = base8 + 32768;
  unsigned short* WqTl = base8 + 81920;
  unsigned short* btPad = base8 + 131072;

  prep_kernel<<<dim3(339), dim3(256), 0, stream>>>(w_qkv, w_merge, bias_table,
                                                   WqTh, WqTl, WhT, WlT, btPad);
  qkv_kernel<<<dim3(1000), dim3(256), 0, stream>>>(x, b_qkv, WqTh, WqTl,
                                                   Qh, Ql, Kh, Kl, Vt);
  attn7_kernel<<<dim3(8000), dim3(256), 0, stream>>>(Qh, Ql, Kh, Kl, Vt, btPad, Oh, Ol);
  merge3_kernel<<<dim3(2000), dim3(256), 0, stream>>>(Oh, Ol, WhT, WlT, b_merge, out);
}